// Round 1
// baseline (197.336 us; speedup 1.0000x reference)
//
#include <hip/hip_runtime.h>
#include <type_traits>
#include <utility>

#define NT 2048   // tokens
#define HD 1024   // hidden
#define NHEAD 16
#define DHEAD 64

typedef float f32x4 __attribute__((ext_vector_type(4)));
typedef __bf16 b16x8 __attribute__((ext_vector_type(8)));
typedef short s16x8 __attribute__((ext_vector_type(8)));
typedef unsigned short u16x8 __attribute__((ext_vector_type(8)));
typedef unsigned short u16x4 __attribute__((ext_vector_type(4)));

// ---- MFMA builtin signature dispatch (bf16-vector vs short-vector toolchains) ----
template <typename V, typename = void>
struct mfma_takes : std::false_type {};
template <typename V>
struct mfma_takes<V, std::void_t<decltype(__builtin_amdgcn_mfma_f32_16x16x32_bf16(
                         std::declval<V>(), std::declval<V>(), std::declval<f32x4>(), 0, 0, 0))>>
    : std::true_type {};

template <typename V>
__device__ __forceinline__ f32x4 mfma_impl(V a, V b, f32x4 c) {
  return __builtin_amdgcn_mfma_f32_16x16x32_bf16(a, b, c, 0, 0, 0);
}

__device__ __forceinline__ f32x4 mfma_bf16(u16x8 a, u16x8 b, f32x4 c) {
  using V = typename std::conditional<mfma_takes<b16x8>::value, b16x8, s16x8>::type;
  return mfma_impl<V>(__builtin_bit_cast(V, a), __builtin_bit_cast(V, b), c);
}

__device__ __forceinline__ unsigned short f2bf(float f) {
  unsigned int u = __builtin_bit_cast(unsigned int, f);
  return (unsigned short)((u + 0x7FFFu + ((u >> 16) & 1u)) >> 16);
}

// =====================================================================
// Kernel 1: QKV projection GEMM.  C[n,m] = X[n,:] . W[m,:] + b[m]
// z=0: Q (scaled by 0.125, row-major bf16 [N][HD])
// z=1: K (row-major bf16 [N][HD])
// z=2: V (TRANSPOSED bf16 [HD][N] so attention reads V along k contiguously)
// =====================================================================
__global__ __launch_bounds__(256) void proj_gemm(
    const float* __restrict__ qin, const float* __restrict__ kin, const float* __restrict__ vin,
    const float* __restrict__ Wq, const float* __restrict__ bq,
    const float* __restrict__ Wk, const float* __restrict__ bk,
    const float* __restrict__ Wv, const float* __restrict__ bv,
    unsigned short* __restrict__ Qh, unsigned short* __restrict__ Kh,
    unsigned short* __restrict__ Vt) {
  const int z = blockIdx.z;
  const float* X = (z == 0) ? qin : (z == 1) ? kin : vin;
  const float* W = (z == 0) ? Wq : (z == 1) ? Wk : Wv;
  const float* bias = (z == 0) ? bq : (z == 1) ? bk : bv;

  const int n0 = blockIdx.x * 128;
  const int m0 = blockIdx.y * 128;

  __shared__ unsigned short As[128][72];  // bf16, pad 64->72 (144B rows, 16B aligned)
  __shared__ unsigned short Bs[128][72];

  const int tid = threadIdx.x;
  const int lane = tid & 63;
  const int wave = tid >> 6;
  const int wr = wave >> 1, wc = wave & 1;

  f32x4 acc[4][4] = {};

  const int sr = tid >> 4;          // 0..15
  const int sc = (tid & 15) << 2;   // 0..60 (4 fp32 each)

  for (int kt = 0; kt < HD; kt += 64) {
    __syncthreads();
#pragma unroll
    for (int p = 0; p < 8; ++p) {
      const int r = sr + p * 16;
      f32x4 fa = *reinterpret_cast<const f32x4*>(&X[(size_t)(n0 + r) * HD + kt + sc]);
      f32x4 fb = *reinterpret_cast<const f32x4*>(&W[(size_t)(m0 + r) * HD + kt + sc]);
      u16x4 ha, hb;
#pragma unroll
      for (int e = 0; e < 4; ++e) { ha[e] = f2bf(fa[e]); hb[e] = f2bf(fb[e]); }
      *reinterpret_cast<u16x4*>(&As[r][sc]) = ha;
      *reinterpret_cast<u16x4*>(&Bs[r][sc]) = hb;
    }
    __syncthreads();
#pragma unroll
    for (int ks = 0; ks < 2; ++ks) {
      const int kcol = ks * 32 + (lane >> 4) * 8;
      u16x8 a[4], b[4];
#pragma unroll
      for (int i = 0; i < 4; ++i)
        a[i] = *reinterpret_cast<const u16x8*>(&As[wr * 64 + i * 16 + (lane & 15)][kcol]);
#pragma unroll
      for (int i = 0; i < 4; ++i)
        b[i] = *reinterpret_cast<const u16x8*>(&Bs[wc * 64 + i * 16 + (lane & 15)][kcol]);
#pragma unroll
      for (int i = 0; i < 4; ++i)
#pragma unroll
        for (int j = 0; j < 4; ++j)
          acc[i][j] = mfma_bf16(a[i], b[j], acc[i][j]);
    }
  }

  const int rgrp = (lane >> 4) * 4;
#pragma unroll
  for (int i = 0; i < 4; ++i) {
    const int nb = n0 + wr * 64 + i * 16 + rgrp;
#pragma unroll
    for (int j = 0; j < 4; ++j) {
      const int m = m0 + wc * 64 + j * 16 + (lane & 15);
      const float bb = bias[m];
      if (z == 2) {
        u16x4 pk;
#pragma unroll
        for (int r = 0; r < 4; ++r) pk[r] = f2bf(acc[i][j][r] + bb);
        *reinterpret_cast<u16x4*>(&Vt[(size_t)m * NT + nb]) = pk;  // transposed store
      } else {
        unsigned short* dst = (z == 0) ? Qh : Kh;
        const float sc2 = (z == 0) ? 0.125f : 1.0f;  // fold 1/sqrt(d) into Q
#pragma unroll
        for (int r = 0; r < 4; ++r)
          dst[(size_t)(nb + r) * HD + m] = f2bf((acc[i][j][r] + bb) * sc2);
      }
    }
  }
}

// =====================================================================
// Kernel 2: flash attention with additive bias.
// grid = (NT/64, NHEAD), 256 threads = 4 waves, each wave owns 16 q-rows.
// =====================================================================
__global__ __launch_bounds__(256) void attn_kernel(
    const unsigned short* __restrict__ Qh, const unsigned short* __restrict__ Kh,
    const unsigned short* __restrict__ Vt, const float* __restrict__ bias,
    unsigned short* __restrict__ ctx) {
  const int h = blockIdx.y;
  const int q0 = blockIdx.x * 64;
  const int tid = threadIdx.x;
  const int lane = tid & 63;
  const int wave = tid >> 6;

  __shared__ unsigned short Ks[128][72];      // K tile [krow][d]
  __shared__ unsigned short Vs[64][136];      // V tile transposed [d][krow]
  __shared__ unsigned short Ps[4][16][136];   // per-wave P [qrow][krow]

  u16x8 qf[2];
  {
    const int qrow = q0 + wave * 16 + (lane & 15);
    const int db = (lane >> 4) * 8;
    qf[0] = *reinterpret_cast<const u16x8*>(&Qh[(size_t)qrow * HD + h * DHEAD + db]);
    qf[1] = *reinterpret_cast<const u16x8*>(&Qh[(size_t)qrow * HD + h * DHEAD + 32 + db]);
  }

  f32x4 oacc[4] = {};
  float mrun[4], lrun[4];
#pragma unroll
  for (int r = 0; r < 4; ++r) { mrun[r] = -3.0e38f; lrun[r] = 0.f; }

  const float* bias_h = bias + (size_t)h * NT * NT;
  const int qlrow = q0 + wave * 16 + (lane >> 4) * 4;  // + r

  const int ksr = tid >> 3, ksc = (tid & 7) << 3;
  const int vsd = tid >> 2, vsc = (tid & 3) << 3;

  for (int kt = 0; kt < NT; kt += 128) {
    __syncthreads();
    // stage K tile (rows kt..kt+127, head slice) and V^T tile
#pragma unroll
    for (int p = 0; p < 4; ++p) {
      const int r = ksr + p * 32;
      *reinterpret_cast<u16x8*>(&Ks[r][ksc]) =
          *reinterpret_cast<const u16x8*>(&Kh[(size_t)(kt + r) * HD + h * DHEAD + ksc]);
    }
#pragma unroll
    for (int p = 0; p < 4; ++p) {
      const int c = vsc + p * 32;
      *reinterpret_cast<u16x8*>(&Vs[vsd][c]) =
          *reinterpret_cast<const u16x8*>(&Vt[(size_t)(h * DHEAD + vsd) * NT + kt + c]);
    }
    __syncthreads();

    // scores: S[16q x 128k] per wave
    f32x4 s[8] = {};
#pragma unroll
    for (int ks = 0; ks < 2; ++ks) {
      const int kcol = ks * 32 + (lane >> 4) * 8;
#pragma unroll
      for (int j = 0; j < 8; ++j) {
        u16x8 kf = *reinterpret_cast<const u16x8*>(&Ks[j * 16 + (lane & 15)][kcol]);
        s[j] = mfma_bf16(qf[ks], kf, s[j]);
      }
    }
    // + bias (streamed fp32, at C-fragment coordinates)
    const float* bp = bias_h + (size_t)qlrow * NT + kt + (lane & 15);
#pragma unroll
    for (int j = 0; j < 8; ++j)
#pragma unroll
      for (int r = 0; r < 4; ++r)
        s[j][r] += bp[(size_t)r * NT + j * 16];

    // online softmax: row max (in-lane over 8 frags, then 16-lane group reduce)
    float mnew[4];
#pragma unroll
    for (int r = 0; r < 4; ++r) {
      float mx = s[0][r];
#pragma unroll
      for (int j = 1; j < 8; ++j) mx = fmaxf(mx, s[j][r]);
      mx = fmaxf(mx, __shfl_xor(mx, 1));
      mx = fmaxf(mx, __shfl_xor(mx, 2));
      mx = fmaxf(mx, __shfl_xor(mx, 4));
      mx = fmaxf(mx, __shfl_xor(mx, 8));
      mnew[r] = fmaxf(mrun[r], mx);
    }
#pragma unroll
    for (int r = 0; r < 4; ++r) {
      const float corr = exp2f((mrun[r] - mnew[r]) * 1.44269504f);
      lrun[r] *= corr;
#pragma unroll
      for (int nd = 0; nd < 4; ++nd) oacc[nd][r] *= corr;
      mrun[r] = mnew[r];
    }
    float psum[4] = {0.f, 0.f, 0.f, 0.f};
#pragma unroll
    for (int j = 0; j < 8; ++j)
#pragma unroll
      for (int r = 0; r < 4; ++r) {
        const float p = exp2f((s[j][r] - mrun[r]) * 1.44269504f);
        psum[r] += p;
        Ps[wave][(lane >> 4) * 4 + r][j * 16 + (lane & 15)] = f2bf(p);
      }
#pragma unroll
    for (int r = 0; r < 4; ++r) {
      float t = psum[r];
      t += __shfl_xor(t, 1);
      t += __shfl_xor(t, 2);
      t += __shfl_xor(t, 4);
      t += __shfl_xor(t, 8);
      lrun[r] += t;
    }
    __syncthreads();  // make P visible across lanes (and drain before PV reads)

    // PV: O[16q x 64d] += P[16q x 128k] . V[128k x 64d]
#pragma unroll
    for (int kk = 0; kk < 4; ++kk) {
      const int kcol = kk * 32 + (lane >> 4) * 8;
      u16x8 pa = *reinterpret_cast<const u16x8*>(&Ps[wave][lane & 15][kcol]);
#pragma unroll
      for (int nd = 0; nd < 4; ++nd) {
        u16x8 vb = *reinterpret_cast<const u16x8*>(&Vs[nd * 16 + (lane & 15)][kcol]);
        oacc[nd] = mfma_bf16(pa, vb, oacc[nd]);
      }
    }
  }

#pragma unroll
  for (int nd = 0; nd < 4; ++nd)
#pragma unroll
    for (int r = 0; r < 4; ++r) {
      const float val = oacc[nd][r] / lrun[r];
      ctx[(size_t)(qlrow + r) * HD + h * DHEAD + nd * 16 + (lane & 15)] = f2bf(val);
    }
}

// =====================================================================
// Kernel 3: output projection.  out[n,m] = ctx[n,:] . Wo[m,:] + bo[m]  (fp32 out)
// =====================================================================
__global__ __launch_bounds__(256) void out_gemm(
    const unsigned short* __restrict__ Ain, const float* __restrict__ W,
    const float* __restrict__ bias, float* __restrict__ out) {
  const int n0 = blockIdx.x * 128;
  const int m0 = blockIdx.y * 128;

  __shared__ unsigned short As[128][72];
  __shared__ unsigned short Bs[128][72];

  const int tid = threadIdx.x;
  const int lane = tid & 63;
  const int wave = tid >> 6;
  const int wr = wave >> 1, wc = wave & 1;

  f32x4 acc[4][4] = {};

  const int ar = tid >> 3, ac = (tid & 7) << 3;
  const int br = tid >> 4, bc = (tid & 15) << 2;

  for (int kt = 0; kt < HD; kt += 64) {
    __syncthreads();
#pragma unroll
    for (int p = 0; p < 4; ++p) {
      const int r = ar + p * 32;
      *reinterpret_cast<u16x8*>(&As[r][ac]) =
          *reinterpret_cast<const u16x8*>(&Ain[(size_t)(n0 + r) * HD + kt + ac]);
    }
#pragma unroll
    for (int p = 0; p < 8; ++p) {
      const int r = br + p * 16;
      f32x4 fb = *reinterpret_cast<const f32x4*>(&W[(size_t)(m0 + r) * HD + kt + bc]);
      u16x4 hb;
#pragma unroll
      for (int e = 0; e < 4; ++e) hb[e] = f2bf(fb[e]);
      *reinterpret_cast<u16x4*>(&Bs[r][bc]) = hb;
    }
    __syncthreads();
#pragma unroll
    for (int ks = 0; ks < 2; ++ks) {
      const int kcol = ks * 32 + (lane >> 4) * 8;
      u16x8 a[4], b[4];
#pragma unroll
      for (int i = 0; i < 4; ++i)
        a[i] = *reinterpret_cast<const u16x8*>(&As[wr * 64 + i * 16 + (lane & 15)][kcol]);
#pragma unroll
      for (int i = 0; i < 4; ++i)
        b[i] = *reinterpret_cast<const u16x8*>(&Bs[wc * 64 + i * 16 + (lane & 15)][kcol]);
#pragma unroll
      for (int i = 0; i < 4; ++i)
#pragma unroll
        for (int j = 0; j < 4; ++j)
          acc[i][j] = mfma_bf16(a[i], b[j], acc[i][j]);
    }
  }

  const int rgrp = (lane >> 4) * 4;
#pragma unroll
  for (int i = 0; i < 4; ++i) {
    const int nb = n0 + wr * 64 + i * 16 + rgrp;
#pragma unroll
    for (int j = 0; j < 4; ++j) {
      const int m = m0 + wc * 64 + j * 16 + (lane & 15);
      const float bb = bias[m];
#pragma unroll
      for (int r = 0; r < 4; ++r)
        out[(size_t)(nb + r) * HD + m] = acc[i][j][r] + bb;
    }
  }
}

extern "C" void kernel_launch(void* const* d_in, const int* in_sizes, int n_in,
                              void* d_out, int out_size, void* d_ws, size_t ws_size,
                              hipStream_t stream) {
  const float* q  = (const float*)d_in[0];
  const float* k  = (const float*)d_in[1];
  const float* v  = (const float*)d_in[2];
  const float* ab = (const float*)d_in[3];
  const float* Wq = (const float*)d_in[4];
  const float* bq = (const float*)d_in[5];
  const float* Wk = (const float*)d_in[6];
  const float* bk = (const float*)d_in[7];
  const float* Wv = (const float*)d_in[8];
  const float* bv = (const float*)d_in[9];
  const float* Wo = (const float*)d_in[10];
  const float* bo = (const float*)d_in[11];

  unsigned short* Qh  = (unsigned short*)d_ws;          // [NT][HD] bf16 (pre-scaled)
  unsigned short* Kh  = Qh + (size_t)NT * HD;           // [NT][HD] bf16
  unsigned short* Vt  = Kh + (size_t)NT * HD;           // [HD][NT] bf16 (transposed)
  unsigned short* ctx = Vt + (size_t)NT * HD;           // [NT][HD] bf16

  proj_gemm<<<dim3(NT / 128, HD / 128, 3), 256, 0, stream>>>(
      q, k, v, Wq, bq, Wk, bk, Wv, bv, Qh, Kh, Vt);
  attn_kernel<<<dim3(NT / 64, NHEAD), 256, 0, stream>>>(Qh, Kh, Vt, ab, ctx);
  out_gemm<<<dim3(NT / 128, HD / 128), 256, 0, stream>>>(ctx, Wo, bo, (float*)d_out);
}

// Round 2
// 147.436 us; speedup vs baseline: 1.3385x; 1.3385x over previous
//
#include <hip/hip_runtime.h>
#include <type_traits>
#include <utility>

#define NT 2048   // tokens
#define HD 1024   // hidden
#define NHEAD 16
#define DHEAD 64
#define LOG2E 1.44269504f

typedef float f32x4 __attribute__((ext_vector_type(4)));
typedef __bf16 b16x8 __attribute__((ext_vector_type(8)));
typedef short s16x8 __attribute__((ext_vector_type(8)));
typedef unsigned short u16x8 __attribute__((ext_vector_type(8)));
typedef unsigned short u16x4 __attribute__((ext_vector_type(4)));

// ---- MFMA builtin signature dispatch (bf16-vector vs short-vector toolchains) ----
template <typename V, typename = void>
struct mfma_takes : std::false_type {};
template <typename V>
struct mfma_takes<V, std::void_t<decltype(__builtin_amdgcn_mfma_f32_16x16x32_bf16(
                         std::declval<V>(), std::declval<V>(), std::declval<f32x4>(), 0, 0, 0))>>
    : std::true_type {};

template <typename V>
__device__ __forceinline__ f32x4 mfma_impl(V a, V b, f32x4 c) {
  return __builtin_amdgcn_mfma_f32_16x16x32_bf16(a, b, c, 0, 0, 0);
}

__device__ __forceinline__ f32x4 mfma_bf16(u16x8 a, u16x8 b, f32x4 c) {
  using V = typename std::conditional<mfma_takes<b16x8>::value, b16x8, s16x8>::type;
  return mfma_impl<V>(__builtin_bit_cast(V, a), __builtin_bit_cast(V, b), c);
}

__device__ __forceinline__ unsigned short f2bf(float f) {
  unsigned int u = __builtin_bit_cast(unsigned int, f);
  return (unsigned short)((u + 0x7FFFu + ((u >> 16) & 1u)) >> 16);
}

// async global->LDS, 16B per lane
__device__ __forceinline__ void gload16(const unsigned short* g, unsigned short* l) {
  __builtin_amdgcn_global_load_lds(
      (__attribute__((address_space(1))) void*)(void*)(g),
      (__attribute__((address_space(3))) void*)(void*)(l), 16, 0, 0);
}

// =====================================================================
// Kernel 0: fp32 -> bf16 conversion of q,k,v and the 4 weight matrices.
// grid = (512, 7); segs 0..2 are [NT*HD], 3..6 are [HD*HD].
// =====================================================================
__global__ __launch_bounds__(256) void cvt_bf16(
    const float* __restrict__ s0, const float* __restrict__ s1, const float* __restrict__ s2,
    const float* __restrict__ s3, const float* __restrict__ s4, const float* __restrict__ s5,
    const float* __restrict__ s6,
    unsigned short* __restrict__ d0, unsigned short* __restrict__ d1, unsigned short* __restrict__ d2,
    unsigned short* __restrict__ d3, unsigned short* __restrict__ d4, unsigned short* __restrict__ d5,
    unsigned short* __restrict__ d6) {
  const int seg = blockIdx.y;
  const float* s;
  unsigned short* d;
  switch (seg) {
    case 0: s = s0; d = d0; break;
    case 1: s = s1; d = d1; break;
    case 2: s = s2; d = d2; break;
    case 3: s = s3; d = d3; break;
    case 4: s = s4; d = d4; break;
    case 5: s = s5; d = d5; break;
    default: s = s6; d = d6; break;
  }
  const int n = (seg < 3) ? NT * HD : HD * HD;
  for (int i = blockIdx.x * 2048 + threadIdx.x * 8; i < n; i += gridDim.x * 2048) {
    f32x4 f0 = *reinterpret_cast<const f32x4*>(&s[i]);
    f32x4 f1 = *reinterpret_cast<const f32x4*>(&s[i + 4]);
    u16x8 o;
#pragma unroll
    for (int e = 0; e < 4; ++e) { o[e] = f2bf(f0[e]); o[e + 4] = f2bf(f1[e]); }
    *reinterpret_cast<u16x8*>(&d[i]) = o;
  }
}

// =====================================================================
// GEMM mainloop: C(128x128) = A_tile . B_tile^T, A/B bf16 row-major [*][K=HD],
// staged via global_load_lds (linear LDS, m97 2-barrier structure).
// =====================================================================
__device__ __forceinline__ void gemm_mainloop(
    const unsigned short* __restrict__ A, const unsigned short* __restrict__ B,
    unsigned short* As, unsigned short* Bs, int n0, int m0, f32x4 acc[4][4]) {
  const int tid = threadIdx.x;
  const int lane = tid & 63;
  const int wr = (tid >> 6) >> 1, wc = (tid >> 6) & 1;
  const int srow = tid >> 3;          // 0..31
  const int scol = (tid & 7) << 3;    // u16 col 0..56

  for (int kt = 0; kt < HD; kt += 64) {
    __syncthreads();
#pragma unroll
    for (int i = 0; i < 4; ++i) {
      gload16(&A[(size_t)(n0 + srow + i * 32) * HD + kt + scol], As + i * 2048 + tid * 8);
      gload16(&B[(size_t)(m0 + srow + i * 32) * HD + kt + scol], Bs + i * 2048 + tid * 8);
    }
    __syncthreads();
#pragma unroll
    for (int ks = 0; ks < 2; ++ks) {
      const int kcol = ks * 32 + (lane >> 4) * 8;
      u16x8 a[4], b[4];
#pragma unroll
      for (int i = 0; i < 4; ++i)
        a[i] = *reinterpret_cast<const u16x8*>(&As[(wr * 64 + i * 16 + (lane & 15)) * 64 + kcol]);
#pragma unroll
      for (int j = 0; j < 4; ++j)
        b[j] = *reinterpret_cast<const u16x8*>(&Bs[(wc * 64 + j * 16 + (lane & 15)) * 64 + kcol]);
#pragma unroll
      for (int i = 0; i < 4; ++i)
#pragma unroll
        for (int j = 0; j < 4; ++j)
          acc[i][j] = mfma_bf16(a[i], b[j], acc[i][j]);
    }
  }
}

// =====================================================================
// Kernel 1: fused QKV projection (z = 0/1/2), bf16 inputs.
// z=0: Q scaled by 0.125*log2(e), row-major. z=1: K row-major.
// z=2: V stored transposed [HD][NT].
// =====================================================================
__global__ __launch_bounds__(256) void proj_gemm(
    const unsigned short* __restrict__ qb, const unsigned short* __restrict__ kb,
    const unsigned short* __restrict__ vb,
    const unsigned short* __restrict__ Wqb, const unsigned short* __restrict__ Wkb,
    const unsigned short* __restrict__ Wvb,
    const float* __restrict__ bq, const float* __restrict__ bk, const float* __restrict__ bv,
    unsigned short* __restrict__ Qh, unsigned short* __restrict__ Kh,
    unsigned short* __restrict__ Vt) {
  const int z = blockIdx.z;
  const unsigned short* A = (z == 0) ? qb : (z == 1) ? kb : vb;
  const unsigned short* B = (z == 0) ? Wqb : (z == 1) ? Wkb : Wvb;
  const float* bias = (z == 0) ? bq : (z == 1) ? bk : bv;

  __shared__ unsigned short As[128 * 64];
  __shared__ unsigned short Bs[128 * 64];

  const int n0 = blockIdx.x * 128;
  const int m0 = blockIdx.y * 128;
  const int tid = threadIdx.x;
  const int lane = tid & 63;
  const int wr = (tid >> 6) >> 1, wc = (tid >> 6) & 1;

  f32x4 acc[4][4] = {};
  gemm_mainloop(A, B, As, Bs, n0, m0, acc);

  const int rgrp = (lane >> 4) * 4;
  const float scale = (z == 0) ? 0.125f * LOG2E : 1.0f;
#pragma unroll
  for (int i = 0; i < 4; ++i) {
    const int nb = n0 + wr * 64 + i * 16 + rgrp;
#pragma unroll
    for (int j = 0; j < 4; ++j) {
      const int m = m0 + wc * 64 + j * 16 + (lane & 15);
      const float bb = bias[m];
      if (z == 2) {
        u16x4 pk;
#pragma unroll
        for (int r = 0; r < 4; ++r) pk[r] = f2bf(acc[i][j][r] + bb);
        *reinterpret_cast<u16x4*>(&Vt[(size_t)m * NT + nb]) = pk;  // transposed store
      } else {
        unsigned short* dst = (z == 0) ? Qh : Kh;
#pragma unroll
        for (int r = 0; r < 4; ++r)
          dst[(size_t)(nb + r) * HD + m] = f2bf((acc[i][j][r] + bb) * scale);
      }
    }
  }
}

// =====================================================================
// Kernel 2: flash attention with additive bias (log2-domain softmax).
// grid = (NT/64, NHEAD), 256 threads = 4 waves x 16 q-rows.
// =====================================================================
__global__ __launch_bounds__(256) void attn_kernel(
    const unsigned short* __restrict__ Qh, const unsigned short* __restrict__ Kh,
    const unsigned short* __restrict__ Vt, const float* __restrict__ bias,
    unsigned short* __restrict__ ctx) {
  const int h = blockIdx.y;
  const int q0 = blockIdx.x * 64;
  const int tid = threadIdx.x;
  const int lane = tid & 63;
  const int wave = tid >> 6;

  __shared__ unsigned short Ks[128][72];      // K tile [krow][d]
  __shared__ unsigned short Vs[64][136];      // V tile transposed [d][krow]
  __shared__ unsigned short Ps[4][16][136];   // per-wave P [qrow][krow]

  u16x8 qf[2];
  {
    const int qrow = q0 + wave * 16 + (lane & 15);
    const int db = (lane >> 4) * 8;
    qf[0] = *reinterpret_cast<const u16x8*>(&Qh[(size_t)qrow * HD + h * DHEAD + db]);
    qf[1] = *reinterpret_cast<const u16x8*>(&Qh[(size_t)qrow * HD + h * DHEAD + 32 + db]);
  }

  f32x4 oacc[4] = {};
  float mrun[4], lrun[4];
#pragma unroll
  for (int r = 0; r < 4; ++r) { mrun[r] = -3.0e38f; lrun[r] = 0.f; }

  const float* bias_h = bias + (size_t)h * NT * NT;
  const int qlrow = q0 + wave * 16 + (lane >> 4) * 4;  // + r

  const int ksr = tid >> 3, ksc = (tid & 7) << 3;
  const int vsd = tid >> 2, vsc = (tid & 3) << 3;
  const unsigned short* Kbase = Kh + h * DHEAD;
  const unsigned short* Vbase = Vt + (size_t)(h * DHEAD + vsd) * NT;

  // stage tile 0
#pragma unroll
  for (int p = 0; p < 4; ++p)
    *reinterpret_cast<u16x8*>(&Ks[ksr + p * 32][ksc]) =
        *reinterpret_cast<const u16x8*>(&Kbase[(size_t)(ksr + p * 32) * HD + ksc]);
#pragma unroll
  for (int p = 0; p < 4; ++p)
    *reinterpret_cast<u16x8*>(&Vs[vsd][vsc + p * 32]) =
        *reinterpret_cast<const u16x8*>(&Vbase[vsc + p * 32]);
  __syncthreads();

  for (int t = 0; t < NT / 128; ++t) {
    const int kt = t * 128;
    // ---- issue bias loads early (latency hides under QK^T MFMA) ----
    float br[8][4];
    const float* bp = bias_h + (size_t)qlrow * NT + kt + (lane & 15);
#pragma unroll
    for (int j = 0; j < 8; ++j)
#pragma unroll
      for (int r = 0; r < 4; ++r) br[j][r] = bp[(size_t)r * NT + j * 16];

    // ---- issue next-tile K/V prefetch into regs ----
    u16x8 kpre[4], vpre[4];
    const bool more = (t + 1 < NT / 128);
    if (more) {
      const int kt2 = kt + 128;
#pragma unroll
      for (int p = 0; p < 4; ++p)
        kpre[p] = *reinterpret_cast<const u16x8*>(&Kbase[(size_t)(kt2 + ksr + p * 32) * HD + ksc]);
#pragma unroll
      for (int p = 0; p < 4; ++p)
        vpre[p] = *reinterpret_cast<const u16x8*>(&Vbase[kt2 + vsc + p * 32]);
    }

    // ---- QK^T (Q pre-scaled by 0.125*log2e) ----
    f32x4 s[8] = {};
#pragma unroll
    for (int ks = 0; ks < 2; ++ks) {
      const int kcol = ks * 32 + (lane >> 4) * 8;
#pragma unroll
      for (int j = 0; j < 8; ++j) {
        u16x8 kf = *reinterpret_cast<const u16x8*>(&Ks[j * 16 + (lane & 15)][kcol]);
        s[j] = mfma_bf16(qf[ks], kf, s[j]);
      }
    }
    // ---- + bias*log2e ----
#pragma unroll
    for (int j = 0; j < 8; ++j)
#pragma unroll
      for (int r = 0; r < 4; ++r) s[j][r] = fmaf(br[j][r], LOG2E, s[j][r]);

    // ---- online softmax (log2 domain) ----
    float mnew[4];
#pragma unroll
    for (int r = 0; r < 4; ++r) {
      float mx = s[0][r];
#pragma unroll
      for (int j = 1; j < 8; ++j) mx = fmaxf(mx, s[j][r]);
      mx = fmaxf(mx, __shfl_xor(mx, 1));
      mx = fmaxf(mx, __shfl_xor(mx, 2));
      mx = fmaxf(mx, __shfl_xor(mx, 4));
      mx = fmaxf(mx, __shfl_xor(mx, 8));
      mnew[r] = fmaxf(mrun[r], mx);
    }
#pragma unroll
    for (int r = 0; r < 4; ++r) {
      const float corr = exp2f(mrun[r] - mnew[r]);
      lrun[r] *= corr;
#pragma unroll
      for (int nd = 0; nd < 4; ++nd) oacc[nd][r] *= corr;
      mrun[r] = mnew[r];
    }
    float psum[4] = {0.f, 0.f, 0.f, 0.f};
#pragma unroll
    for (int j = 0; j < 8; ++j)
#pragma unroll
      for (int r = 0; r < 4; ++r) {
        const float p = exp2f(s[j][r] - mrun[r]);
        psum[r] += p;
        Ps[wave][(lane >> 4) * 4 + r][j * 16 + (lane & 15)] = f2bf(p);
      }
#pragma unroll
    for (int r = 0; r < 4; ++r) {
      float tsum = psum[r];
      tsum += __shfl_xor(tsum, 1);
      tsum += __shfl_xor(tsum, 2);
      tsum += __shfl_xor(tsum, 4);
      tsum += __shfl_xor(tsum, 8);
      lrun[r] += tsum;
    }

    // ---- PV (P round-trip is within-wave: no barrier needed) ----
#pragma unroll
    for (int kk = 0; kk < 4; ++kk) {
      const int kcol = kk * 32 + (lane >> 4) * 8;
      u16x8 pa = *reinterpret_cast<const u16x8*>(&Ps[wave][lane & 15][kcol]);
#pragma unroll
      for (int nd = 0; nd < 4; ++nd) {
        u16x8 vb = *reinterpret_cast<const u16x8*>(&Vs[nd * 16 + (lane & 15)][kcol]);
        oacc[nd] = mfma_bf16(pa, vb, oacc[nd]);
      }
    }
    __syncthreads();  // all waves done reading Ks/Vs
    if (more) {
#pragma unroll
      for (int p = 0; p < 4; ++p)
        *reinterpret_cast<u16x8*>(&Ks[ksr + p * 32][ksc]) = kpre[p];
#pragma unroll
      for (int p = 0; p < 4; ++p)
        *reinterpret_cast<u16x8*>(&Vs[vsd][vsc + p * 32]) = vpre[p];
    }
    __syncthreads();  // staged tile visible
  }

#pragma unroll
  for (int nd = 0; nd < 4; ++nd) {
#pragma unroll
    for (int r = 0; r < 4; ++r) {
      const float val = oacc[nd][r] / lrun[r];
      ctx[(size_t)(qlrow + r) * HD + h * DHEAD + nd * 16 + (lane & 15)] = f2bf(val);
    }
  }
}

// =====================================================================
// Kernel 3: output projection, fp32 out.
// =====================================================================
__global__ __launch_bounds__(256) void out_gemm(
    const unsigned short* __restrict__ Ain, const unsigned short* __restrict__ Wob,
    const float* __restrict__ bias, float* __restrict__ out) {
  __shared__ unsigned short As[128 * 64];
  __shared__ unsigned short Bs[128 * 64];

  const int n0 = blockIdx.x * 128;
  const int m0 = blockIdx.y * 128;
  const int tid = threadIdx.x;
  const int lane = tid & 63;
  const int wr = (tid >> 6) >> 1, wc = (tid >> 6) & 1;

  f32x4 acc[4][4] = {};
  gemm_mainloop(Ain, Wob, As, Bs, n0, m0, acc);

  const int rgrp = (lane >> 4) * 4;
#pragma unroll
  for (int i = 0; i < 4; ++i) {
    const int nb = n0 + wr * 64 + i * 16 + rgrp;
#pragma unroll
    for (int j = 0; j < 4; ++j) {
      const int m = m0 + wc * 64 + j * 16 + (lane & 15);
      const float bb = bias[m];
#pragma unroll
      for (int r = 0; r < 4; ++r)
        out[(size_t)(nb + r) * HD + m] = acc[i][j][r] + bb;
    }
  }
}

extern "C" void kernel_launch(void* const* d_in, const int* in_sizes, int n_in,
                              void* d_out, int out_size, void* d_ws, size_t ws_size,
                              hipStream_t stream) {
  const float* q  = (const float*)d_in[0];
  const float* k  = (const float*)d_in[1];
  const float* v  = (const float*)d_in[2];
  const float* ab = (const float*)d_in[3];
  const float* Wq = (const float*)d_in[4];
  const float* bq = (const float*)d_in[5];
  const float* Wk = (const float*)d_in[6];
  const float* bk = (const float*)d_in[7];
  const float* Wv = (const float*)d_in[8];
  const float* bv = (const float*)d_in[9];
  const float* Wo = (const float*)d_in[10];
  const float* bo = (const float*)d_in[11];

  unsigned short* qb  = (unsigned short*)d_ws;          // [NT][HD]
  unsigned short* kb  = qb + (size_t)NT * HD;
  unsigned short* vb  = kb + (size_t)NT * HD;
  unsigned short* Wqb = vb + (size_t)NT * HD;           // [HD][HD]
  unsigned short* Wkb = Wqb + (size_t)HD * HD;
  unsigned short* Wvb = Wkb + (size_t)HD * HD;
  unsigned short* Wob = Wvb + (size_t)HD * HD;
  unsigned short* Qh  = Wob + (size_t)HD * HD;          // [NT][HD] bf16 (pre-scaled)
  unsigned short* Kh  = Qh + (size_t)NT * HD;           // [NT][HD]
  unsigned short* Vt  = Kh + (size_t)NT * HD;           // [HD][NT] (transposed)
  unsigned short* ctx = Vt + (size_t)NT * HD;           // [NT][HD]

  cvt_bf16<<<dim3(512, 7), 256, 0, stream>>>(q, k, v, Wq, Wk, Wv, Wo,
                                             qb, kb, vb, Wqb, Wkb, Wvb, Wob);
  proj_gemm<<<dim3(NT / 128, HD / 128, 3), 256, 0, stream>>>(
      qb, kb, vb, Wqb, Wkb, Wvb, bq, bk, bv, Qh, Kh, Vt);
  attn_kernel<<<dim3(NT / 64, NHEAD), 256, 0, stream>>>(Qh, Kh, Vt, ab, ctx);
  out_gemm<<<dim3(NT / 128, HD / 128), 256, 0, stream>>>(ctx, Wob, bo, (float*)d_out);
}

// Round 3
// 132.272 us; speedup vs baseline: 1.4919x; 1.1146x over previous
//
#include <hip/hip_runtime.h>
#include <type_traits>
#include <utility>

#define NT 2048   // tokens
#define HD 1024   // hidden
#define NHEAD 16
#define DHEAD 64
#define LOG2E 1.44269504f

typedef float f32x4 __attribute__((ext_vector_type(4)));
typedef __bf16 b16x8 __attribute__((ext_vector_type(8)));
typedef short s16x8 __attribute__((ext_vector_type(8)));
typedef unsigned short u16x8 __attribute__((ext_vector_type(8)));
typedef unsigned short u16x4 __attribute__((ext_vector_type(4)));

// ---- MFMA builtin signature dispatch (bf16-vector vs short-vector toolchains) ----
template <typename V, typename = void>
struct mfma_takes : std::false_type {};
template <typename V>
struct mfma_takes<V, std::void_t<decltype(__builtin_amdgcn_mfma_f32_16x16x32_bf16(
                         std::declval<V>(), std::declval<V>(), std::declval<f32x4>(), 0, 0, 0))>>
    : std::true_type {};

template <typename V>
__device__ __forceinline__ f32x4 mfma_impl(V a, V b, f32x4 c) {
  return __builtin_amdgcn_mfma_f32_16x16x32_bf16(a, b, c, 0, 0, 0);
}

__device__ __forceinline__ f32x4 mfma_bf16(u16x8 a, u16x8 b, f32x4 c) {
  using V = typename std::conditional<mfma_takes<b16x8>::value, b16x8, s16x8>::type;
  return mfma_impl<V>(__builtin_bit_cast(V, a), __builtin_bit_cast(V, b), c);
}

__device__ __forceinline__ unsigned short f2bf(float f) {
  unsigned int u = __builtin_bit_cast(unsigned int, f);
  return (unsigned short)((u + 0x7FFFu + ((u >> 16) & 1u)) >> 16);
}

// async global->LDS, 16B per lane
__device__ __forceinline__ void gload16(const unsigned short* g, unsigned short* l) {
  __builtin_amdgcn_global_load_lds(
      (__attribute__((address_space(1))) void*)(void*)(g),
      (__attribute__((address_space(3))) void*)(void*)(l), 16, 0, 0);
}

// =====================================================================
// Kernel 0: fp32 -> bf16 conversion of q,k,v and the 4 weight matrices.
// =====================================================================
__global__ __launch_bounds__(256) void cvt_bf16(
    const float* __restrict__ s0, const float* __restrict__ s1, const float* __restrict__ s2,
    const float* __restrict__ s3, const float* __restrict__ s4, const float* __restrict__ s5,
    const float* __restrict__ s6,
    unsigned short* __restrict__ d0, unsigned short* __restrict__ d1, unsigned short* __restrict__ d2,
    unsigned short* __restrict__ d3, unsigned short* __restrict__ d4, unsigned short* __restrict__ d5,
    unsigned short* __restrict__ d6) {
  const int seg = blockIdx.y;
  const float* s;
  unsigned short* d;
  switch (seg) {
    case 0: s = s0; d = d0; break;
    case 1: s = s1; d = d1; break;
    case 2: s = s2; d = d2; break;
    case 3: s = s3; d = d3; break;
    case 4: s = s4; d = d4; break;
    case 5: s = s5; d = d5; break;
    default: s = s6; d = d6; break;
  }
  const int n = (seg < 3) ? NT * HD : HD * HD;
  for (int i = blockIdx.x * 2048 + threadIdx.x * 8; i < n; i += gridDim.x * 2048) {
    f32x4 f0 = *reinterpret_cast<const f32x4*>(&s[i]);
    f32x4 f1 = *reinterpret_cast<const f32x4*>(&s[i + 4]);
    u16x8 o;
#pragma unroll
    for (int e = 0; e < 4; ++e) { o[e] = f2bf(f0[e]); o[e + 4] = f2bf(f1[e]); }
    *reinterpret_cast<u16x8*>(&d[i]) = o;
  }
}

// =====================================================================
// Double-buffered 64x128 GEMM mainloop (2-phase: stage(t+1) || compute(t)).
// C[64 x 128] = A[n0:n0+64, :] . B[m0:m0+128, :]^T, bf16, K = HD.
// LDS: As0/As1 64*64 u16 (8KB), Bs0/Bs1 128*64 u16 (16KB). 4 waves (2x2).
// =====================================================================
__device__ __forceinline__ void gemm64x128(
    const unsigned short* __restrict__ A, const unsigned short* __restrict__ B,
    int n0, int m0,
    unsigned short* As0, unsigned short* As1,
    unsigned short* Bs0, unsigned short* Bs1, f32x4 acc[2][4]) {
  const int tid = threadIdx.x;
  const int lane = tid & 63;
  const int wr = (tid >> 6) >> 1, wc = (tid >> 6) & 1;
  const int srow = tid >> 3;        // 0..31
  const int scol = (tid & 7) << 3;  // 0..56

  auto stage = [&](int kt, unsigned short* as, unsigned short* bs) {
#pragma unroll
    for (int p = 0; p < 2; ++p)
      gload16(&A[(size_t)(n0 + p * 32 + srow) * HD + kt + scol], as + p * 2048 + tid * 8);
#pragma unroll
    for (int p = 0; p < 4; ++p)
      gload16(&B[(size_t)(m0 + p * 32 + srow) * HD + kt + scol], bs + p * 2048 + tid * 8);
  };
  auto comp = [&](const unsigned short* as, const unsigned short* bs) {
#pragma unroll
    for (int ks = 0; ks < 2; ++ks) {
      const int kcol = ks * 32 + (lane >> 4) * 8;
      u16x8 a[2], b[4];
#pragma unroll
      for (int i = 0; i < 2; ++i)
        a[i] = *reinterpret_cast<const u16x8*>(&as[(wr * 32 + i * 16 + (lane & 15)) * 64 + kcol]);
#pragma unroll
      for (int j = 0; j < 4; ++j)
        b[j] = *reinterpret_cast<const u16x8*>(&bs[(wc * 64 + j * 16 + (lane & 15)) * 64 + kcol]);
#pragma unroll
      for (int i = 0; i < 2; ++i)
#pragma unroll
        for (int j = 0; j < 4; ++j)
          acc[i][j] = mfma_bf16(a[i], b[j], acc[i][j]);
    }
  };

  stage(0, As0, Bs0);
  __syncthreads();
#pragma unroll 1
  for (int tt = 0; tt < 8; ++tt) {
    const int kt = tt * 128;
    stage(kt + 64, As1, Bs1);        // prefetch next half-step
    comp(As0, Bs0);                  // compute current (loads land during this)
    __syncthreads();                 // vmcnt(0)+lgkmcnt(0)+barrier
    if (kt + 128 < HD) stage(kt + 128, As0, Bs0);
    comp(As1, Bs1);
    __syncthreads();
  }
}

// =====================================================================
// Kernel 1: fused QKV projection. 1D grid 768: L = m*96 + z*32 + n
// (L%8 = n%8 -> the 8 m-blocks of one (z,n) share an XCD/L2 A-panel).
// z=0: Q scaled by 0.125*log2e row-major; z=1: K row-major; z=2: V transposed.
// =====================================================================
__global__ __launch_bounds__(256) void proj_gemm(
    const unsigned short* __restrict__ qb, const unsigned short* __restrict__ kb,
    const unsigned short* __restrict__ vb,
    const unsigned short* __restrict__ Wqb, const unsigned short* __restrict__ Wkb,
    const unsigned short* __restrict__ Wvb,
    const float* __restrict__ bq, const float* __restrict__ bk, const float* __restrict__ bv,
    unsigned short* __restrict__ Qh, unsigned short* __restrict__ Kh,
    unsigned short* __restrict__ Vt) {
  const int L = blockIdx.x;
  const int m = L / 96;
  const int c = L % 96;
  const int z = c / 32;
  const int n = c % 32;
  const int n0 = n * 64, m0 = m * 128;

  const unsigned short* A = (z == 0) ? qb : (z == 1) ? kb : vb;
  const unsigned short* B = (z == 0) ? Wqb : (z == 1) ? Wkb : Wvb;
  const float* bias = (z == 0) ? bq : (z == 1) ? bk : bv;

  __shared__ unsigned short As0[64 * 64], As1[64 * 64];
  __shared__ unsigned short Bs0[128 * 64], Bs1[128 * 64];

  const int tid = threadIdx.x;
  const int lane = tid & 63;
  const int wr = (tid >> 6) >> 1, wc = (tid >> 6) & 1;

  f32x4 acc[2][4] = {};
  gemm64x128(A, B, n0, m0, As0, As1, Bs0, Bs1, acc);

  const int rgrp = (lane >> 4) * 4;
  const float scale = (z == 0) ? 0.125f * LOG2E : 1.0f;
#pragma unroll
  for (int i = 0; i < 2; ++i) {
    const int nb = n0 + wr * 32 + i * 16 + rgrp;
#pragma unroll
    for (int j = 0; j < 4; ++j) {
      const int mcol = m0 + wc * 64 + j * 16 + (lane & 15);
      const float bb = bias[mcol];
      if (z == 2) {
        u16x4 pk;
#pragma unroll
        for (int r = 0; r < 4; ++r) pk[r] = f2bf(acc[i][j][r] + bb);
        *reinterpret_cast<u16x4*>(&Vt[(size_t)mcol * NT + nb]) = pk;  // transposed store
      } else {
        unsigned short* dst = (z == 0) ? Qh : Kh;
#pragma unroll
        for (int r = 0; r < 4; ++r)
          dst[(size_t)(nb + r) * HD + mcol] = f2bf((acc[i][j][r] + bb) * scale);
      }
    }
  }
}

// =====================================================================
// Kernel 2: flash attention with additive bias (log2-domain softmax).
// 1D grid 512: xcd = id&7 owns heads {2*xcd, 2*xcd+1} (K/V L2 locality).
// 256 threads = 4 waves x 16 q-rows.
// =====================================================================
__global__ __launch_bounds__(256) void attn_kernel(
    const unsigned short* __restrict__ Qh, const unsigned short* __restrict__ Kh,
    const unsigned short* __restrict__ Vt, const float* __restrict__ bias,
    unsigned short* __restrict__ ctx) {
  const int id = blockIdx.x;
  const int xcd = id & 7, slot = id >> 3;
  const int h = xcd * 2 + (slot >> 5);
  const int q0 = (slot & 31) * 64;
  const int tid = threadIdx.x;
  const int lane = tid & 63;
  const int wave = tid >> 6;

  __shared__ unsigned short Ks[128][72];      // K tile [krow][d]
  __shared__ unsigned short Vs[64][136];      // V tile transposed [d][krow]
  __shared__ unsigned short Ps[4][16][136];   // per-wave P [qrow][krow]

  u16x8 qf[2];
  {
    const int qrow = q0 + wave * 16 + (lane & 15);
    const int db = (lane >> 4) * 8;
    qf[0] = *reinterpret_cast<const u16x8*>(&Qh[(size_t)qrow * HD + h * DHEAD + db]);
    qf[1] = *reinterpret_cast<const u16x8*>(&Qh[(size_t)qrow * HD + h * DHEAD + 32 + db]);
  }

  f32x4 oacc[4] = {};
  float mrun[4], lrun[4];
#pragma unroll
  for (int r = 0; r < 4; ++r) { mrun[r] = -3.0e38f; lrun[r] = 0.f; }

  const float* bias_h = bias + (size_t)h * NT * NT;
  const int qlrow = q0 + wave * 16 + (lane >> 4) * 4;  // + r

  const int ksr = tid >> 3, ksc = (tid & 7) << 3;
  const int vsd = tid >> 2, vsc = (tid & 3) << 3;
  const unsigned short* Kbase = Kh + h * DHEAD;
  const unsigned short* Vbase = Vt + (size_t)(h * DHEAD + vsd) * NT;

  // stage tile 0
#pragma unroll
  for (int p = 0; p < 4; ++p)
    *reinterpret_cast<u16x8*>(&Ks[ksr + p * 32][ksc]) =
        *reinterpret_cast<const u16x8*>(&Kbase[(size_t)(ksr + p * 32) * HD + ksc]);
#pragma unroll
  for (int p = 0; p < 4; ++p)
    *reinterpret_cast<u16x8*>(&Vs[vsd][vsc + p * 32]) =
        *reinterpret_cast<const u16x8*>(&Vbase[vsc + p * 32]);
  __syncthreads();

  for (int t = 0; t < NT / 128; ++t) {
    const int kt = t * 128;
    // ---- issue bias loads early (latency hides under QK^T MFMA) ----
    float br[8][4];
    const float* bp = bias_h + (size_t)qlrow * NT + kt + (lane & 15);
#pragma unroll
    for (int j = 0; j < 8; ++j)
#pragma unroll
      for (int r = 0; r < 4; ++r) br[j][r] = bp[(size_t)r * NT + j * 16];

    // ---- issue next-tile K/V prefetch into regs ----
    u16x8 kpre[4], vpre[4];
    const bool more = (t + 1 < NT / 128);
    if (more) {
      const int kt2 = kt + 128;
#pragma unroll
      for (int p = 0; p < 4; ++p)
        kpre[p] = *reinterpret_cast<const u16x8*>(&Kbase[(size_t)(kt2 + ksr + p * 32) * HD + ksc]);
#pragma unroll
      for (int p = 0; p < 4; ++p)
        vpre[p] = *reinterpret_cast<const u16x8*>(&Vbase[kt2 + vsc + p * 32]);
    }

    // ---- QK^T (Q pre-scaled by 0.125*log2e) ----
    f32x4 s[8] = {};
#pragma unroll
    for (int ks = 0; ks < 2; ++ks) {
      const int kcol = ks * 32 + (lane >> 4) * 8;
#pragma unroll
      for (int j = 0; j < 8; ++j) {
        u16x8 kf = *reinterpret_cast<const u16x8*>(&Ks[j * 16 + (lane & 15)][kcol]);
        s[j] = mfma_bf16(qf[ks], kf, s[j]);
      }
    }
    // ---- + bias*log2e ----
#pragma unroll
    for (int j = 0; j < 8; ++j)
#pragma unroll
      for (int r = 0; r < 4; ++r) s[j][r] = fmaf(br[j][r], LOG2E, s[j][r]);

    // ---- online softmax (log2 domain) ----
    float mnew[4];
#pragma unroll
    for (int r = 0; r < 4; ++r) {
      float mx = s[0][r];
#pragma unroll
      for (int j = 1; j < 8; ++j) mx = fmaxf(mx, s[j][r]);
      mx = fmaxf(mx, __shfl_xor(mx, 1));
      mx = fmaxf(mx, __shfl_xor(mx, 2));
      mx = fmaxf(mx, __shfl_xor(mx, 4));
      mx = fmaxf(mx, __shfl_xor(mx, 8));
      mnew[r] = fmaxf(mrun[r], mx);
    }
#pragma unroll
    for (int r = 0; r < 4; ++r) {
      const float corr = exp2f(mrun[r] - mnew[r]);
      lrun[r] *= corr;
#pragma unroll
      for (int nd = 0; nd < 4; ++nd) oacc[nd][r] *= corr;
      mrun[r] = mnew[r];
    }
    float psum[4] = {0.f, 0.f, 0.f, 0.f};
#pragma unroll
    for (int j = 0; j < 8; ++j)
#pragma unroll
      for (int r = 0; r < 4; ++r) {
        const float p = exp2f(s[j][r] - mrun[r]);
        psum[r] += p;
        Ps[wave][(lane >> 4) * 4 + r][j * 16 + (lane & 15)] = f2bf(p);
      }
#pragma unroll
    for (int r = 0; r < 4; ++r) {
      float tsum = psum[r];
      tsum += __shfl_xor(tsum, 1);
      tsum += __shfl_xor(tsum, 2);
      tsum += __shfl_xor(tsum, 4);
      tsum += __shfl_xor(tsum, 8);
      lrun[r] += tsum;
    }

    // ---- PV (P round-trip is within-wave: no barrier needed) ----
#pragma unroll
    for (int kk = 0; kk < 4; ++kk) {
      const int kcol = kk * 32 + (lane >> 4) * 8;
      u16x8 pa = *reinterpret_cast<const u16x8*>(&Ps[wave][lane & 15][kcol]);
#pragma unroll
      for (int nd = 0; nd < 4; ++nd) {
        u16x8 vb = *reinterpret_cast<const u16x8*>(&Vs[nd * 16 + (lane & 15)][kcol]);
        oacc[nd] = mfma_bf16(pa, vb, oacc[nd]);
      }
    }
    __syncthreads();  // all waves done reading Ks/Vs
    if (more) {
#pragma unroll
      for (int p = 0; p < 4; ++p)
        *reinterpret_cast<u16x8*>(&Ks[ksr + p * 32][ksc]) = kpre[p];
#pragma unroll
      for (int p = 0; p < 4; ++p)
        *reinterpret_cast<u16x8*>(&Vs[vsd][vsc + p * 32]) = vpre[p];
    }
    __syncthreads();  // staged tile visible
  }

#pragma unroll
  for (int nd = 0; nd < 4; ++nd) {
#pragma unroll
    for (int r = 0; r < 4; ++r) {
      const float val = oacc[nd][r] / lrun[r];
      ctx[(size_t)(qlrow + r) * HD + h * DHEAD + nd * 16 + (lane & 15)] = f2bf(val);
    }
  }
}

// =====================================================================
// Kernel 3: output projection, fp32 out. 1D grid 256: L = m*32 + n.
// =====================================================================
__global__ __launch_bounds__(256) void out_gemm(
    const unsigned short* __restrict__ Ain, const unsigned short* __restrict__ Wob,
    const float* __restrict__ bias, float* __restrict__ out) {
  const int L = blockIdx.x;
  const int m = L / 32;
  const int n = L % 32;
  const int n0 = n * 64, m0 = m * 128;

  __shared__ unsigned short As0[64 * 64], As1[64 * 64];
  __shared__ unsigned short Bs0[128 * 64], Bs1[128 * 64];

  const int tid = threadIdx.x;
  const int lane = tid & 63;
  const int wr = (tid >> 6) >> 1, wc = (tid >> 6) & 1;

  f32x4 acc[2][4] = {};
  gemm64x128(Ain, Wob, n0, m0, As0, As1, Bs0, Bs1, acc);

  const int rgrp = (lane >> 4) * 4;
#pragma unroll
  for (int i = 0; i < 2; ++i) {
    const int nb = n0 + wr * 32 + i * 16 + rgrp;
#pragma unroll
    for (int j = 0; j < 4; ++j) {
      const int mcol = m0 + wc * 64 + j * 16 + (lane & 15);
      const float bb = bias[mcol];
#pragma unroll
      for (int r = 0; r < 4; ++r)
        out[(size_t)(nb + r) * HD + mcol] = acc[i][j][r] + bb;
    }
  }
}

extern "C" void kernel_launch(void* const* d_in, const int* in_sizes, int n_in,
                              void* d_out, int out_size, void* d_ws, size_t ws_size,
                              hipStream_t stream) {
  const float* q  = (const float*)d_in[0];
  const float* k  = (const float*)d_in[1];
  const float* v  = (const float*)d_in[2];
  const float* ab = (const float*)d_in[3];
  const float* Wq = (const float*)d_in[4];
  const float* bq = (const float*)d_in[5];
  const float* Wk = (const float*)d_in[6];
  const float* bk = (const float*)d_in[7];
  const float* Wv = (const float*)d_in[8];
  const float* bv = (const float*)d_in[9];
  const float* Wo = (const float*)d_in[10];
  const float* bo = (const float*)d_in[11];

  unsigned short* qb  = (unsigned short*)d_ws;          // [NT][HD]
  unsigned short* kb  = qb + (size_t)NT * HD;
  unsigned short* vb  = kb + (size_t)NT * HD;
  unsigned short* Wqb = vb + (size_t)NT * HD;           // [HD][HD]
  unsigned short* Wkb = Wqb + (size_t)HD * HD;
  unsigned short* Wvb = Wkb + (size_t)HD * HD;
  unsigned short* Wob = Wvb + (size_t)HD * HD;
  unsigned short* Qh  = Wob + (size_t)HD * HD;          // [NT][HD] bf16 (pre-scaled)
  unsigned short* Kh  = Qh + (size_t)NT * HD;           // [NT][HD]
  unsigned short* Vt  = Kh + (size_t)NT * HD;           // [HD][NT] (transposed)
  unsigned short* ctx = Vt + (size_t)NT * HD;           // [NT][HD]

  cvt_bf16<<<dim3(512, 7), 256, 0, stream>>>(q, k, v, Wq, Wk, Wv, Wo,
                                             qb, kb, vb, Wqb, Wkb, Wvb, Wob);
  proj_gemm<<<dim3(768), 256, 0, stream>>>(
      qb, kb, vb, Wqb, Wkb, Wvb, bq, bk, bv, Qh, Kh, Vt);
  attn_kernel<<<dim3(512), 256, 0, stream>>>(Qh, Kh, Vt, ab, ctx);
  out_gemm<<<dim3(256), 256, 0, stream>>>(ctx, Wob, bo, (float*)d_out);
}

// Round 4
// 124.497 us; speedup vs baseline: 1.5851x; 1.0624x over previous
//
#include <hip/hip_runtime.h>
#include <type_traits>
#include <utility>

#define NT 2048   // tokens
#define HD 1024   // hidden
#define NHEAD 16
#define DHEAD 64
#define LOG2E 1.44269504f

typedef float f32x4 __attribute__((ext_vector_type(4)));
typedef __bf16 b16x8 __attribute__((ext_vector_type(8)));
typedef short s16x8 __attribute__((ext_vector_type(8)));
typedef unsigned short u16x8 __attribute__((ext_vector_type(8)));
typedef unsigned short u16x4 __attribute__((ext_vector_type(4)));

// ---- MFMA builtin signature dispatch (bf16-vector vs short-vector toolchains) ----
template <typename V, typename = void>
struct mfma_takes : std::false_type {};
template <typename V>
struct mfma_takes<V, std::void_t<decltype(__builtin_amdgcn_mfma_f32_16x16x32_bf16(
                         std::declval<V>(), std::declval<V>(), std::declval<f32x4>(), 0, 0, 0))>>
    : std::true_type {};

template <typename V>
__device__ __forceinline__ f32x4 mfma_impl(V a, V b, f32x4 c) {
  return __builtin_amdgcn_mfma_f32_16x16x32_bf16(a, b, c, 0, 0, 0);
}

__device__ __forceinline__ f32x4 mfma_bf16(u16x8 a, u16x8 b, f32x4 c) {
  using V = typename std::conditional<mfma_takes<b16x8>::value, b16x8, s16x8>::type;
  return mfma_impl<V>(__builtin_bit_cast(V, a), __builtin_bit_cast(V, b), c);
}

__device__ __forceinline__ unsigned short f2bf(float f) {
  unsigned int u = __builtin_bit_cast(unsigned int, f);
  return (unsigned short)((u + 0x7FFFu + ((u >> 16) & 1u)) >> 16);
}

// async global->LDS, 16B per lane
__device__ __forceinline__ void gload16(const unsigned short* g, unsigned short* l) {
  __builtin_amdgcn_global_load_lds(
      (__attribute__((address_space(1))) void*)(void*)(g),
      (__attribute__((address_space(3))) void*)(void*)(l), 16, 0, 0);
}

// raw barrier pinned against compile-time motion of LDS/VMEM ops
__device__ __forceinline__ void barrier_pinned() {
  __builtin_amdgcn_sched_barrier(0);
  __builtin_amdgcn_s_barrier();
  __builtin_amdgcn_sched_barrier(0);
}
#define WAIT_VM6() asm volatile("s_waitcnt vmcnt(6)" ::: "memory")
#define WAIT_VM0() asm volatile("s_waitcnt vmcnt(0)" ::: "memory")
#define WAIT_LGKM0() asm volatile("s_waitcnt lgkmcnt(0)" ::: "memory")

// =====================================================================
// Kernel 0: fp32 -> bf16 conversion of q,k,v and the 4 weight matrices.
// =====================================================================
__global__ __launch_bounds__(256) void cvt_bf16(
    const float* __restrict__ s0, const float* __restrict__ s1, const float* __restrict__ s2,
    const float* __restrict__ s3, const float* __restrict__ s4, const float* __restrict__ s5,
    const float* __restrict__ s6,
    unsigned short* __restrict__ d0, unsigned short* __restrict__ d1, unsigned short* __restrict__ d2,
    unsigned short* __restrict__ d3, unsigned short* __restrict__ d4, unsigned short* __restrict__ d5,
    unsigned short* __restrict__ d6) {
  const int seg = blockIdx.y;
  const float* s;
  unsigned short* d;
  switch (seg) {
    case 0: s = s0; d = d0; break;
    case 1: s = s1; d = d1; break;
    case 2: s = s2; d = d2; break;
    case 3: s = s3; d = d3; break;
    case 4: s = s4; d = d4; break;
    case 5: s = s5; d = d5; break;
    default: s = s6; d = d6; break;
  }
  const int n = (seg < 3) ? NT * HD : HD * HD;
  for (int i = blockIdx.x * 2048 + threadIdx.x * 8; i < n; i += gridDim.x * 2048) {
    f32x4 f0 = *reinterpret_cast<const f32x4*>(&s[i]);
    f32x4 f1 = *reinterpret_cast<const f32x4*>(&s[i + 4]);
    u16x8 o;
#pragma unroll
    for (int e = 0; e < 4; ++e) { o[e] = f2bf(f0[e]); o[e + 4] = f2bf(f1[e]); }
    *reinterpret_cast<u16x8*>(&d[i]) = o;
  }
}

// =====================================================================
// 64x128 GEMM mainloop: counted-vmcnt double-buffer pipeline (T3/T4-lite)
// with T2 XOR-swizzled LDS (swizzle applied on the GLOBAL source so the
// gload_lds destination stays linear; reads XOR the chunk with row&7).
// C[64 x 128] = A[n0:, :] . B[m0:, :]^T, bf16, K = HD. 4 waves (2x2).
// =====================================================================
__device__ __forceinline__ void gemm64x128(
    const unsigned short* __restrict__ A, const unsigned short* __restrict__ B,
    int n0, int m0,
    unsigned short* As0, unsigned short* As1,
    unsigned short* Bs0, unsigned short* Bs1, f32x4 acc[2][4]) {
  const int tid = threadIdx.x;
  const int lane = tid & 63;
  const int wr = (tid >> 6) >> 1, wc = (tid >> 6) & 1;
  const int srow = tid >> 3;                              // 0..31
  const int scol = (((tid & 7) ^ (srow & 7)) << 3);       // swizzled source chunk

  auto stage = [&](int kt, unsigned short* as, unsigned short* bs) {
#pragma unroll
    for (int p = 0; p < 2; ++p)
      gload16(&A[(size_t)(n0 + p * 32 + srow) * HD + kt + scol], as + p * 2048 + tid * 8);
#pragma unroll
    for (int p = 0; p < 4; ++p)
      gload16(&B[(size_t)(m0 + p * 32 + srow) * HD + kt + scol], bs + p * 2048 + tid * 8);
  };
  auto comp = [&](const unsigned short* as, const unsigned short* bs) {
#pragma unroll
    for (int ks = 0; ks < 2; ++ks) {
      const int q = ks * 4 + (lane >> 4);  // 16B-chunk index 0..7
      u16x8 a[2], b[4];
#pragma unroll
      for (int i = 0; i < 2; ++i) {
        const int row = wr * 32 + i * 16 + (lane & 15);
        a[i] = *reinterpret_cast<const u16x8*>(&as[row * 64 + ((q ^ (row & 7)) << 3)]);
      }
#pragma unroll
      for (int j = 0; j < 4; ++j) {
        const int row = wc * 64 + j * 16 + (lane & 15);
        b[j] = *reinterpret_cast<const u16x8*>(&bs[row * 64 + ((q ^ (row & 7)) << 3)]);
      }
#pragma unroll
      for (int i = 0; i < 2; ++i)
#pragma unroll
        for (int j = 0; j < 4; ++j)
          acc[i][j] = mfma_bf16(a[i], b[j], acc[i][j]);
    }
  };

  // prologue: two K-steps in flight (12 loads)
  stage(0, As0, Bs0);
  stage(64, As1, Bs1);
#pragma unroll 1
  for (int s = 0; s < 14; ++s) {
    WAIT_VM6();          // oldest stage (s) complete; stage s+1 still in flight
    barrier_pinned();    // all waves' stage-s writes visible
    if (s & 1) comp(As1, Bs1); else comp(As0, Bs0);
    barrier_pinned();    // all waves done reading buffer (s&1)
    if (s & 1) stage((s + 2) * 64, As1, Bs1);
    else       stage((s + 2) * 64, As0, Bs0);
  }
  WAIT_VM6();            // stage 14 done (stage 15 in flight)
  barrier_pinned();
  comp(As0, Bs0);
  WAIT_VM0();            // stage 15 done
  barrier_pinned();
  comp(As1, Bs1);
}

// =====================================================================
// Kernel 1: fused QKV projection. 1D grid 768: L = m*96 + z*32 + n
// (L%8 = n%8 -> the 8 m-blocks of one (z,n) share an XCD/L2 A-panel).
// z=0: Q scaled by 0.125*log2e row-major; z=1: K row-major; z=2: V transposed.
// =====================================================================
__global__ __launch_bounds__(256) void proj_gemm(
    const unsigned short* __restrict__ qb, const unsigned short* __restrict__ kb,
    const unsigned short* __restrict__ vb,
    const unsigned short* __restrict__ Wqb, const unsigned short* __restrict__ Wkb,
    const unsigned short* __restrict__ Wvb,
    const float* __restrict__ bq, const float* __restrict__ bk, const float* __restrict__ bv,
    unsigned short* __restrict__ Qh, unsigned short* __restrict__ Kh,
    unsigned short* __restrict__ Vt) {
  const int L = blockIdx.x;
  const int m = L / 96;
  const int c = L % 96;
  const int z = c / 32;
  const int n = c % 32;
  const int n0 = n * 64, m0 = m * 128;

  const unsigned short* A = (z == 0) ? qb : (z == 1) ? kb : vb;
  const unsigned short* B = (z == 0) ? Wqb : (z == 1) ? Wkb : Wvb;
  const float* bias = (z == 0) ? bq : (z == 1) ? bk : bv;

  __shared__ unsigned short As0[64 * 64], As1[64 * 64];
  __shared__ unsigned short Bs0[128 * 64], Bs1[128 * 64];

  const int tid = threadIdx.x;
  const int lane = tid & 63;
  const int wr = (tid >> 6) >> 1, wc = (tid >> 6) & 1;

  f32x4 acc[2][4] = {};
  gemm64x128(A, B, n0, m0, As0, As1, Bs0, Bs1, acc);

  const int rgrp = (lane >> 4) * 4;
  const float scale = (z == 0) ? 0.125f * LOG2E : 1.0f;
#pragma unroll
  for (int i = 0; i < 2; ++i) {
    const int nb = n0 + wr * 32 + i * 16 + rgrp;
#pragma unroll
    for (int j = 0; j < 4; ++j) {
      const int mcol = m0 + wc * 64 + j * 16 + (lane & 15);
      const float bb = bias[mcol];
      if (z == 2) {
        u16x4 pk;
#pragma unroll
        for (int r = 0; r < 4; ++r) pk[r] = f2bf(acc[i][j][r] + bb);
        *reinterpret_cast<u16x4*>(&Vt[(size_t)mcol * NT + nb]) = pk;  // transposed store
      } else {
        unsigned short* dst = (z == 0) ? Qh : Kh;
#pragma unroll
        for (int r = 0; r < 4; ++r)
          dst[(size_t)(nb + r) * HD + mcol] = f2bf((acc[i][j][r] + bb) * scale);
      }
    }
  }
}

// =====================================================================
// Kernel 2: flash attention with additive bias (log2-domain softmax).
// 1D grid 512: xcd = id&7 owns heads {2*xcd, 2*xcd+1} (K/V L2 locality).
// 256 threads = 4 waves x 16 q-rows. Raw barriers (no vmcnt drain) so
// bias(t+1) + K/V reg-prefetch loads stay in flight across iterations.
// =====================================================================
__global__ __launch_bounds__(256) void attn_kernel(
    const unsigned short* __restrict__ Qh, const unsigned short* __restrict__ Kh,
    const unsigned short* __restrict__ Vt, const float* __restrict__ bias,
    unsigned short* __restrict__ ctx) {
  const int id = blockIdx.x;
  const int xcd = id & 7, slot = id >> 3;
  const int h = xcd * 2 + (slot >> 5);
  const int q0 = (slot & 31) * 64;
  const int tid = threadIdx.x;
  const int lane = tid & 63;
  const int wave = tid >> 6;

  __shared__ unsigned short Ks[128][72];      // K tile [krow][d]
  __shared__ unsigned short Vs[64][136];      // V tile transposed [d][krow]
  __shared__ unsigned short Ps[4][16][136];   // per-wave P [qrow][krow]

  u16x8 qf[2];
  {
    const int qrow = q0 + wave * 16 + (lane & 15);
    const int db = (lane >> 4) * 8;
    qf[0] = *reinterpret_cast<const u16x8*>(&Qh[(size_t)qrow * HD + h * DHEAD + db]);
    qf[1] = *reinterpret_cast<const u16x8*>(&Qh[(size_t)qrow * HD + h * DHEAD + 32 + db]);
  }

  f32x4 oacc[4] = {};
  float mrun[4], lrun[4];
#pragma unroll
  for (int r = 0; r < 4; ++r) { mrun[r] = -3.0e38f; lrun[r] = 0.f; }

  const float* bias_h = bias + (size_t)h * NT * NT;
  const int qlrow = q0 + wave * 16 + (lane >> 4) * 4;  // + r

  const int ksr = tid >> 3, ksc = (tid & 7) << 3;
  const int vsd = tid >> 2, vsc = (tid & 3) << 3;
  const unsigned short* Kbase = Kh + h * DHEAD;
  const unsigned short* Vbase = Vt + (size_t)(h * DHEAD + vsd) * NT;

  // ---- prologue: bias tile 0 into regs ----
  float br[8][4];
  {
    const float* bp = bias_h + (size_t)qlrow * NT + (lane & 15);
#pragma unroll
    for (int j = 0; j < 8; ++j)
#pragma unroll
      for (int r = 0; r < 4; ++r) br[j][r] = bp[(size_t)r * NT + j * 16];
  }
  // ---- prologue: stage K/V tile 0 ----
#pragma unroll
  for (int p = 0; p < 4; ++p)
    *reinterpret_cast<u16x8*>(&Ks[ksr + p * 32][ksc]) =
        *reinterpret_cast<const u16x8*>(&Kbase[(size_t)(ksr + p * 32) * HD + ksc]);
#pragma unroll
  for (int p = 0; p < 4; ++p)
    *reinterpret_cast<u16x8*>(&Vs[vsd][vsc + p * 32]) =
        *reinterpret_cast<const u16x8*>(&Vbase[vsc + p * 32]);
  WAIT_LGKM0();
  barrier_pinned();

#pragma unroll 1
  for (int t = 0; t < NT / 128; ++t) {
    // ---- QK^T (Q pre-scaled by 0.125*log2e) ----
    f32x4 s[8] = {};
#pragma unroll
    for (int ks = 0; ks < 2; ++ks) {
      const int kcol = ks * 32 + (lane >> 4) * 8;
#pragma unroll
      for (int j = 0; j < 8; ++j) {
        u16x8 kf = *reinterpret_cast<const u16x8*>(&Ks[j * 16 + (lane & 15)][kcol]);
        s[j] = mfma_bf16(qf[ks], kf, s[j]);
      }
    }
    // ---- consume bias tile t ----
#pragma unroll
    for (int j = 0; j < 8; ++j)
#pragma unroll
      for (int r = 0; r < 4; ++r) s[j][r] = fmaf(br[j][r], LOG2E, s[j][r]);

    // ---- prefetch: bias tile t+1 + K/V tile t+1 (stay in flight across
    //      the raw barriers; consumed next iteration) ----
    const bool more = (t + 1 < NT / 128);
    u16x8 kpre[4], vpre[4];
    if (more) {
      const int kt2 = (t + 1) * 128;
      const float* bp = bias_h + (size_t)qlrow * NT + kt2 + (lane & 15);
#pragma unroll
      for (int j = 0; j < 8; ++j)
#pragma unroll
        for (int r = 0; r < 4; ++r) br[j][r] = bp[(size_t)r * NT + j * 16];
#pragma unroll
      for (int p = 0; p < 4; ++p)
        kpre[p] = *reinterpret_cast<const u16x8*>(&Kbase[(size_t)(kt2 + ksr + p * 32) * HD + ksc]);
#pragma unroll
      for (int p = 0; p < 4; ++p)
        vpre[p] = *reinterpret_cast<const u16x8*>(&Vbase[kt2 + vsc + p * 32]);
    }

    // ---- online softmax (log2 domain) ----
    float mnew[4];
#pragma unroll
    for (int r = 0; r < 4; ++r) {
      float mx = s[0][r];
#pragma unroll
      for (int j = 1; j < 8; ++j) mx = fmaxf(mx, s[j][r]);
      mx = fmaxf(mx, __shfl_xor(mx, 1));
      mx = fmaxf(mx, __shfl_xor(mx, 2));
      mx = fmaxf(mx, __shfl_xor(mx, 4));
      mx = fmaxf(mx, __shfl_xor(mx, 8));
      mnew[r] = fmaxf(mrun[r], mx);
    }
#pragma unroll
    for (int r = 0; r < 4; ++r) {
      const float corr = exp2f(mrun[r] - mnew[r]);
      lrun[r] *= corr;
#pragma unroll
      for (int nd = 0; nd < 4; ++nd) oacc[nd][r] *= corr;
      mrun[r] = mnew[r];
    }
    float psum[4] = {0.f, 0.f, 0.f, 0.f};
#pragma unroll
    for (int j = 0; j < 8; ++j)
#pragma unroll
      for (int r = 0; r < 4; ++r) {
        const float p = exp2f(s[j][r] - mrun[r]);
        psum[r] += p;
        Ps[wave][(lane >> 4) * 4 + r][j * 16 + (lane & 15)] = f2bf(p);
      }
#pragma unroll
    for (int r = 0; r < 4; ++r) {
      float tsum = psum[r];
      tsum += __shfl_xor(tsum, 1);
      tsum += __shfl_xor(tsum, 2);
      tsum += __shfl_xor(tsum, 4);
      tsum += __shfl_xor(tsum, 8);
      lrun[r] += tsum;
    }

    // ---- PV (P round-trip is within-wave; compiler orders via lgkmcnt) ----
#pragma unroll
    for (int kk = 0; kk < 4; ++kk) {
      const int kcol = kk * 32 + (lane >> 4) * 8;
      u16x8 pa = *reinterpret_cast<const u16x8*>(&Ps[wave][lane & 15][kcol]);
#pragma unroll
      for (int nd = 0; nd < 4; ++nd) {
        u16x8 vb = *reinterpret_cast<const u16x8*>(&Vs[nd * 16 + (lane & 15)][kcol]);
        oacc[nd] = mfma_bf16(pa, vb, oacc[nd]);
      }
    }

    barrier_pinned();   // all waves done reading Ks/Vs (reads completed: MFMA consumed them)
    if (more) {
#pragma unroll
      for (int p = 0; p < 4; ++p)
        *reinterpret_cast<u16x8*>(&Ks[ksr + p * 32][ksc]) = kpre[p];
#pragma unroll
      for (int p = 0; p < 4; ++p)
        *reinterpret_cast<u16x8*>(&Vs[vsd][vsc + p * 32]) = vpre[p];
    }
    WAIT_LGKM0();       // LDS writes complete before visibility barrier
    barrier_pinned();   // staged tile t+1 visible
  }

#pragma unroll
  for (int nd = 0; nd < 4; ++nd) {
#pragma unroll
    for (int r = 0; r < 4; ++r) {
      const float val = oacc[nd][r] / lrun[r];
      ctx[(size_t)(qlrow + r) * HD + h * DHEAD + nd * 16 + (lane & 15)] = f2bf(val);
    }
  }
}

// =====================================================================
// Kernel 3: output projection, fp32 out. 1D grid 256: L = m*32 + n.
// =====================================================================
__global__ __launch_bounds__(256) void out_gemm(
    const unsigned short* __restrict__ Ain, const unsigned short* __restrict__ Wob,
    const float* __restrict__ bias, float* __restrict__ out) {
  const int L = blockIdx.x;
  const int m = L / 32;
  const int n = L % 32;
  const int n0 = n * 64, m0 = m * 128;

  __shared__ unsigned short As0[64 * 64], As1[64 * 64];
  __shared__ unsigned short Bs0[128 * 64], Bs1[128 * 64];

  const int tid = threadIdx.x;
  const int lane = tid & 63;
  const int wr = (tid >> 6) >> 1, wc = (tid >> 6) & 1;

  f32x4 acc[2][4] = {};
  gemm64x128(Ain, Wob, n0, m0, As0, As1, Bs0, Bs1, acc);

  const int rgrp = (lane >> 4) * 4;
#pragma unroll
  for (int i = 0; i < 2; ++i) {
    const int nb = n0 + wr * 32 + i * 16 + rgrp;
#pragma unroll
    for (int j = 0; j < 4; ++j) {
      const int mcol = m0 + wc * 64 + j * 16 + (lane & 15);
      const float bb = bias[mcol];
#pragma unroll
      for (int r = 0; r < 4; ++r)
        out[(size_t)(nb + r) * HD + mcol] = acc[i][j][r] + bb;
    }
  }
}

extern "C" void kernel_launch(void* const* d_in, const int* in_sizes, int n_in,
                              void* d_out, int out_size, void* d_ws, size_t ws_size,
                              hipStream_t stream) {
  const float* q  = (const float*)d_in[0];
  const float* k  = (const float*)d_in[1];
  const float* v  = (const float*)d_in[2];
  const float* ab = (const float*)d_in[3];
  const float* Wq = (const float*)d_in[4];
  const float* bq = (const float*)d_in[5];
  const float* Wk = (const float*)d_in[6];
  const float* bk = (const float*)d_in[7];
  const float* Wv = (const float*)d_in[8];
  const float* bv = (const float*)d_in[9];
  const float* Wo = (const float*)d_in[10];
  const float* bo = (const float*)d_in[11];

  unsigned short* qb  = (unsigned short*)d_ws;          // [NT][HD]
  unsigned short* kb  = qb + (size_t)NT * HD;
  unsigned short* vb  = kb + (size_t)NT * HD;
  unsigned short* Wqb = vb + (size_t)NT * HD;           // [HD][HD]
  unsigned short* Wkb = Wqb + (size_t)HD * HD;
  unsigned short* Wvb = Wkb + (size_t)HD * HD;
  unsigned short* Wob = Wvb + (size_t)HD * HD;
  unsigned short* Qh  = Wob + (size_t)HD * HD;          // [NT][HD] bf16 (pre-scaled)
  unsigned short* Kh  = Qh + (size_t)NT * HD;           // [NT][HD]
  unsigned short* Vt  = Kh + (size_t)NT * HD;           // [HD][NT] (transposed)
  unsigned short* ctx = Vt + (size_t)NT * HD;           // [NT][HD]

  cvt_bf16<<<dim3(512, 7), 256, 0, stream>>>(q, k, v, Wq, Wk, Wv, Wo,
                                             qb, kb, vb, Wqb, Wkb, Wvb, Wob);
  proj_gemm<<<dim3(768), 256, 0, stream>>>(
      qb, kb, vb, Wqb, Wkb, Wvb, bq, bk, bv, Qh, Kh, Vt);
  attn_kernel<<<dim3(512), 256, 0, stream>>>(Qh, Kh, Vt, ab, ctx);
  out_gemm<<<dim3(256), 256, 0, stream>>>(ctx, Wob, bo, (float*)d_out);
}